// Round 2
// baseline (244.179 us; speedup 1.0000x reference)
//
#include <hip/hip_runtime.h>
#include <hip/hip_bf16.h>
#include <math.h>

#define BB 128   // batch
#define NN 96    // perturbations
#define DD 3072  // C*H*W
#define KK 10    // classes
#define SPL 8    // K-splits = waves per block in k1
#define KST 12   // MFMA K-steps per wave: 3072 / (SPL*32)

typedef short s16x8 __attribute__((ext_vector_type(8)));
typedef float f32x4 __attribute__((ext_vector_type(4)));

// ---------------- Kernel 0: pack W into B-fragment layout ----------------
// Record r (0..6143): col=r&15, quad=(r>>4)&3, kb=r>>6. 16B record holds
// bf16 W[kb*32+quad*8+j][col], j=0..7 (zero for col>=10). Lane `l` of
// K-block kb then reads record kb*64+l with ONE coalesced dwordx4.
__global__ __launch_bounds__(256) void k0_pack(
    const float* __restrict__ W, unsigned short* __restrict__ pwg)
{
    const int r = blockIdx.x * 256 + threadIdx.x;   // 0..6143
    const int col  = r & 15;
    const int quad = (r >> 4) & 3;
    const int kb   = r >> 6;
    union { unsigned short us[8]; uint4 v; } rec;
#pragma unroll
    for (int j = 0; j < 8; ++j) {
        const int k = kb * 32 + quad * 8 + j;
        const float v = (col < KK) ? W[k * KK + col] : 0.0f;
        const __hip_bfloat16 h = __float2bfloat16(v);
        __builtin_memcpy(&rec.us[j], &h, 2);
    }
    ((uint4*)pwg)[r] = rec.v;
}

// ---------------- Kernel 1: MFMA logits + per-(n,b) losses ----------------
// grid = 768 blocks (one 16-row M-tile: rows r0..r0+15 = same n, b0..b0+15),
// block = 512 threads = 8 waves = 8 K-splits of 384. Each wave runs 12
// mfma_f32_16x16x32_bf16 steps; A built on the fly (clip(imgs+deltas)->bf16),
// B-frags are single coalesced 16B loads from pwg. LDS reduce + epilogue.
//
// v2: manual 1-ahead software pipeline (issue step s+1's 5 loads before
// step s's VALU+MFMA), nontemporal loads on the zero-reuse deltas stream
// (via ext_vector f32x4 — builtin rejects HIP_vector_type float4), and
// __launch_bounds__(512,6) to keep VGPR<=84 so 3 blocks/CU are resident.
__global__ __launch_bounds__(512, 6) void k1_mfma(
    const float* __restrict__ imgs,    // (128, 3072)
    const float* __restrict__ deltas,  // (96, 128, 3072)
    const unsigned short* __restrict__ pwg,
    const float* __restrict__ bias,    // (10)
    const int*   __restrict__ labels,  // (128)
    float* __restrict__ l1_ws,         // (128, 96)
    float* __restrict__ l2_ws)         // (128, 96)
{
    const int lane = threadIdx.x & 63;
    const int wv   = threadIdx.x >> 6;      // 0..7 = K-split
    const int tile = blockIdx.x;            // 0..767
    const int r0   = tile * 16;
    const int n    = r0 >> 7;               // constant over tile
    const int b0   = r0 & 127;
    const int m    = lane & 15;             // A row within tile
    const int quad = lane >> 4;

    const float* ap = deltas + (size_t)(r0 + m) * DD + wv * (KST * 32) + quad * 8;
    const float* ip = imgs   + (size_t)(b0 + m) * DD + wv * (KST * 32) + quad * 8;
    const unsigned short* wp = pwg + ((size_t)(wv * KST) * 64 + lane) * 8;

    // --- pipeline prologue: step 0 loads in flight ---
    f32x4 d0 = __builtin_nontemporal_load((const f32x4*)(ap));
    f32x4 d1 = __builtin_nontemporal_load((const f32x4*)(ap + 4));
    f32x4 i0 = *(const f32x4*)(ip);
    f32x4 i1 = *(const f32x4*)(ip + 4);
    s16x8 bfrag = *(const s16x8*)(wp);

    f32x4 acc = {0.f, 0.f, 0.f, 0.f};
#pragma unroll
    for (int s = 0; s < KST - 1; ++s) {
        // issue next step's loads FIRST (stay in flight across this step's math)
        const f32x4 nd0 = __builtin_nontemporal_load((const f32x4*)(ap + 32));
        const f32x4 nd1 = __builtin_nontemporal_load((const f32x4*)(ap + 36));
        const f32x4 ni0 = *(const f32x4*)(ip + 32);
        const f32x4 ni1 = *(const f32x4*)(ip + 36);
        const s16x8 nbf = *(const s16x8*)(wp + 512);

        s16x8 afrag;
#pragma unroll
        for (int j = 0; j < 4; ++j) {
            const float xc0 = fminf(fmaxf(d0[j] + i0[j], 0.f), 1.f);
            const float xc1 = fminf(fmaxf(d1[j] + i1[j], 0.f), 1.f);
            const __hip_bfloat16 h0 = __float2bfloat16(xc0);
            const __hip_bfloat16 h1 = __float2bfloat16(xc1);
            unsigned short us0, us1;
            __builtin_memcpy(&us0, &h0, 2);
            __builtin_memcpy(&us1, &h1, 2);
            afrag[j]     = (short)us0;
            afrag[j + 4] = (short)us1;
        }
        acc = __builtin_amdgcn_mfma_f32_16x16x32_bf16(afrag, bfrag, acc, 0, 0, 0);

        d0 = nd0; d1 = nd1; i0 = ni0; i1 = ni1; bfrag = nbf;
        ap += 32; ip += 32; wp += 512;
    }
    {   // peeled last step (no prefetch -> no OOB read on the final row)
        s16x8 afrag;
#pragma unroll
        for (int j = 0; j < 4; ++j) {
            const float xc0 = fminf(fmaxf(d0[j] + i0[j], 0.f), 1.f);
            const float xc1 = fminf(fmaxf(d1[j] + i1[j], 0.f), 1.f);
            const __hip_bfloat16 h0 = __float2bfloat16(xc0);
            const __hip_bfloat16 h1 = __float2bfloat16(xc1);
            unsigned short us0, us1;
            __builtin_memcpy(&us0, &h0, 2);
            __builtin_memcpy(&us1, &h1, 2);
            afrag[j]     = (short)us0;
            afrag[j + 4] = (short)us1;
        }
        acc = __builtin_amdgcn_mfma_f32_16x16x32_bf16(afrag, bfrag, acc, 0, 0, 0);
    }

    // C layout (m89-verified): col = lane&15, row = quad*4 + reg.
    __shared__ float sred[SPL][16][16];     // 8 KB
#pragma unroll
    for (int reg = 0; reg < 4; ++reg)
        sred[wv][quad * 4 + reg][m] = acc[reg];
    __syncthreads();

    if (wv == 0 && lane < 16) {
        const int rr = lane;                // tile row -> b = b0+rr
        float lg[KK];
#pragma unroll
        for (int k = 0; k < KK; ++k) {
            float s = 0.f;
#pragma unroll
            for (int sp = 0; sp < SPL; ++sp) s += sred[sp][rr][k];
            lg[k] = s + bias[k];
        }
        // top-1 (first max -> lower index on ties, matches lax.top_k)
        int top1 = 0; float m1 = lg[0];
#pragma unroll
        for (int k = 1; k < KK; ++k) if (lg[k] > m1) { m1 = lg[k]; top1 = k; }
        int sec = (top1 == 0) ? 1 : 0; float m2 = lg[sec];
#pragma unroll
        for (int k = 0; k < KK; ++k)
            if (k != top1 && lg[k] > m2) { m2 = lg[k]; sec = k; }
        float se = 0.f;
#pragma unroll
        for (int k = 0; k < KK; ++k) se += expf(lg[k] - m1);
        const float lse = m1 + logf(se);
        const int b = b0 + rr;
        const int lab = labels[b];
        const float loss1 = lse - lg[lab];
        const float loss2 = (top1 == lab) ? (lse - lg[sec]) : -10000.0f;
        l1_ws[b * NN + n] = loss1;
        l2_ws[b * NN + n] = loss2;
    }
}

// ---------------- Kernel 2: per-b stable rank-ind selection ----------------
__global__ __launch_bounds__(128) void k2_select(
    const float* __restrict__ l1_ws, const float* __restrict__ l2_ws,
    const int* __restrict__ ind_p, float* __restrict__ perb)
{
    const int b = blockIdx.x;
    const int t = threadIdx.x;
    __shared__ float sd[NN];
    __shared__ float sl2[NN];
    __shared__ float ssel;
    __shared__ float swsum[2];

    float myl1 = 0.f, myd = 0.f;
    if (t < NN) {
        const float a = l1_ws[b * NN + t];
        const float c = l2_ws[b * NN + t];
        myl1 = a; myd = a - c;
        sd[t] = myd; sl2[t] = c;
    }
    __syncthreads();

    if (t < NN) {
        int rank = 0;
        for (int j = 0; j < NN; ++j) {
            const float dj = sd[j];
            rank += (dj < myd) || (dj == myd && j < t);  // stable argsort
        }
        if (rank == ind_p[0]) ssel = sl2[t];
    }

    float s = myl1;
#pragma unroll
    for (int off = 32; off >= 1; off >>= 1) s += __shfl_down(s, off, 64);
    if ((t & 63) == 0) swsum[t >> 6] = s;
    __syncthreads();
    if (t == 0) {
        const float total = swsum[0] + swsum[1];
        perb[b] = total / 96.0f - ssel;
    }
}

// ---------------- Kernel 3: final mean over b ----------------
__global__ __launch_bounds__(128) void k3_final(
    const float* __restrict__ perb, float* __restrict__ out)
{
    const int t = threadIdx.x;
    float s = perb[t];
#pragma unroll
    for (int off = 32; off >= 1; off >>= 1) s += __shfl_down(s, off, 64);
    __shared__ float sw[2];
    if ((t & 63) == 0) sw[t >> 6] = s;
    __syncthreads();
    if (t == 0) out[0] = (sw[0] + sw[1]) / 128.0f;
}

extern "C" void kernel_launch(void* const* d_in, const int* in_sizes, int n_in,
                              void* d_out, int out_size, void* d_ws, size_t ws_size,
                              hipStream_t stream) {
    const float* imgs   = (const float*)d_in[0];
    const float* deltas = (const float*)d_in[1];
    const float* W      = (const float*)d_in[2];
    const float* bias   = (const float*)d_in[3];
    const int*   labels = (const int*)d_in[4];
    const int*   ind    = (const int*)d_in[5];
    float* out = (float*)d_out;

    float* l1_ws = (float*)d_ws;                   // 12288 floats
    float* l2_ws = l1_ws + NN * BB;                // 12288 floats
    float* perb  = l2_ws + NN * BB;                // 128 floats
    unsigned short* pwg = (unsigned short*)(perb + BB);  // 96 KB packed W (16B-aligned)

    k0_pack<<<dim3(24), dim3(256), 0, stream>>>(W, pwg);
    k1_mfma<<<dim3(768), dim3(512), 0, stream>>>(
        imgs, deltas, pwg, bias, labels, l1_ws, l2_ws);
    k2_select<<<dim3(BB), dim3(128), 0, stream>>>(l1_ws, l2_ws, ind, perb);
    k3_final<<<dim3(1), dim3(128), 0, stream>>>(perb, out);
}

// Round 3
// 241.751 us; speedup vs baseline: 1.0100x; 1.0100x over previous
//
#include <hip/hip_runtime.h>
#include <hip/hip_bf16.h>
#include <math.h>

#define BB 128   // batch
#define NN 96    // perturbations
#define DD 3072  // C*H*W
#define KK 10    // classes
#define SPL 8    // K-splits = waves per block in k1
#define KST 12   // MFMA K-steps per wave: 3072 / (SPL*32)

typedef short s16x8 __attribute__((ext_vector_type(8)));
typedef float f32x4 __attribute__((ext_vector_type(4)));

// ---------------- Kernel 0: pack W into B-fragment layout ----------------
// Record r (0..6143): col=r&15, quad=(r>>4)&3, kb=r>>6. 16B record holds
// bf16 W[kb*32+quad*8+j][col], j=0..7 (zero for col>=10). Lane `l` of
// K-block kb then reads record kb*64+l with ONE coalesced dwordx4.
__global__ __launch_bounds__(256) void k0_pack(
    const float* __restrict__ W, unsigned short* __restrict__ pwg)
{
    const int r = blockIdx.x * 256 + threadIdx.x;   // 0..6143
    const int col  = r & 15;
    const int quad = (r >> 4) & 3;
    const int kb   = r >> 6;
    union { unsigned short us[8]; uint4 v; } rec;
#pragma unroll
    for (int j = 0; j < 8; ++j) {
        const int k = kb * 32 + quad * 8 + j;
        const float v = (col < KK) ? W[k * KK + col] : 0.0f;
        const __hip_bfloat16 h = __float2bfloat16(v);
        __builtin_memcpy(&rec.us[j], &h, 2);
    }
    ((uint4*)pwg)[r] = rec.v;
}

// ---------------- Kernel 1: MFMA logits + per-(n,b) losses ----------------
// grid = 768 blocks (one 16-row M-tile: rows r0..r0+15 = same n, b0..b0+15),
// block = 512 threads = 8 waves = 8 K-splits of 384. Each wave runs 12
// mfma_f32_16x16x32_bf16 steps; A built on the fly (clip(imgs+deltas)->bf16),
// B-frags are single coalesced 16B loads from pwg. LDS reduce + epilogue.
//
// v3: 4-step load batching for DRAM page locality. Per wave-step each of the
// 16 rows contributes only 128B, and same-row touches are ~100+ cycles apart
// interleaved with thousands of other row-streams -> each DRAM page is
// activated ~8-16x instead of once. Issuing all 4 steps' deltas loads
// back-to-back makes 512B contiguous bursts per row (4x fewer page visits).
// MFMA order unchanged (s=0..11 sequential) -> bit-identical accumulation.
// Outer loop kept rolled (#pragma unroll 1) to bound VGPRs.
__global__ __launch_bounds__(512) void k1_mfma(
    const float* __restrict__ imgs,    // (128, 3072)
    const float* __restrict__ deltas,  // (96, 128, 3072)
    const unsigned short* __restrict__ pwg,
    const float* __restrict__ bias,    // (10)
    const int*   __restrict__ labels,  // (128)
    float* __restrict__ l1_ws,         // (128, 96)
    float* __restrict__ l2_ws)         // (128, 96)
{
    const int lane = threadIdx.x & 63;
    const int wv   = threadIdx.x >> 6;      // 0..7 = K-split
    const int tile = blockIdx.x;            // 0..767
    const int r0   = tile * 16;
    const int n    = r0 >> 7;               // constant over tile
    const int b0   = r0 & 127;
    const int m    = lane & 15;             // A row within tile
    const int quad = lane >> 4;

    const float* ap = deltas + (size_t)(r0 + m) * DD + wv * (KST * 32) + quad * 8;
    const float* ip = imgs   + (size_t)(b0 + m) * DD + wv * (KST * 32) + quad * 8;
    const unsigned short* wp = pwg + ((size_t)(wv * KST) * 64 + lane) * 8;

    f32x4 acc = {0.f, 0.f, 0.f, 0.f};
#pragma unroll 1
    for (int it = 0; it < KST / 4; ++it) {  // 3 outer iterations x 4 K-steps
        f32x4 d[8];
        f32x4 im[8];
        s16x8 bf[4];
        // deltas burst FIRST: 8 x 16B back-to-back -> 512B/row contiguous
#pragma unroll
        for (int u = 0; u < 4; ++u) {
            d[2 * u]     = *(const f32x4*)(ap + u * 32);
            d[2 * u + 1] = *(const f32x4*)(ap + u * 32 + 4);
        }
#pragma unroll
        for (int u = 0; u < 4; ++u) {
            im[2 * u]     = *(const f32x4*)(ip + u * 32);
            im[2 * u + 1] = *(const f32x4*)(ip + u * 32 + 4);
        }
#pragma unroll
        for (int u = 0; u < 4; ++u)
            bf[u] = *(const s16x8*)(wp + (size_t)u * 512);

#pragma unroll
        for (int u = 0; u < 4; ++u) {
            s16x8 afrag;
#pragma unroll
            for (int j = 0; j < 4; ++j) {
                const float xc0 = fminf(fmaxf(d[2 * u][j]     + im[2 * u][j],     0.f), 1.f);
                const float xc1 = fminf(fmaxf(d[2 * u + 1][j] + im[2 * u + 1][j], 0.f), 1.f);
                const __hip_bfloat16 h0 = __float2bfloat16(xc0);
                const __hip_bfloat16 h1 = __float2bfloat16(xc1);
                unsigned short us0, us1;
                __builtin_memcpy(&us0, &h0, 2);
                __builtin_memcpy(&us1, &h1, 2);
                afrag[j]     = (short)us0;
                afrag[j + 4] = (short)us1;
            }
            acc = __builtin_amdgcn_mfma_f32_16x16x32_bf16(afrag, bf[u], acc, 0, 0, 0);
        }
        ap += 128; ip += 128; wp += 2048;
    }

    // C layout (m89-verified): col = lane&15, row = quad*4 + reg.
    __shared__ float sred[SPL][16][16];     // 8 KB
#pragma unroll
    for (int reg = 0; reg < 4; ++reg)
        sred[wv][quad * 4 + reg][m] = acc[reg];
    __syncthreads();

    if (wv == 0 && lane < 16) {
        const int rr = lane;                // tile row -> b = b0+rr
        float lg[KK];
#pragma unroll
        for (int k = 0; k < KK; ++k) {
            float s = 0.f;
#pragma unroll
            for (int sp = 0; sp < SPL; ++sp) s += sred[sp][rr][k];
            lg[k] = s + bias[k];
        }
        // top-1 (first max -> lower index on ties, matches lax.top_k)
        int top1 = 0; float m1 = lg[0];
#pragma unroll
        for (int k = 1; k < KK; ++k) if (lg[k] > m1) { m1 = lg[k]; top1 = k; }
        int sec = (top1 == 0) ? 1 : 0; float m2 = lg[sec];
#pragma unroll
        for (int k = 0; k < KK; ++k)
            if (k != top1 && lg[k] > m2) { m2 = lg[k]; sec = k; }
        float se = 0.f;
#pragma unroll
        for (int k = 0; k < KK; ++k) se += expf(lg[k] - m1);
        const float lse = m1 + logf(se);
        const int b = b0 + rr;
        const int lab = labels[b];
        const float loss1 = lse - lg[lab];
        const float loss2 = (top1 == lab) ? (lse - lg[sec]) : -10000.0f;
        l1_ws[b * NN + n] = loss1;
        l2_ws[b * NN + n] = loss2;
    }
}

// ---------------- Kernel 2: per-b stable rank-ind selection ----------------
__global__ __launch_bounds__(128) void k2_select(
    const float* __restrict__ l1_ws, const float* __restrict__ l2_ws,
    const int* __restrict__ ind_p, float* __restrict__ perb)
{
    const int b = blockIdx.x;
    const int t = threadIdx.x;
    __shared__ float sd[NN];
    __shared__ float sl2[NN];
    __shared__ float ssel;
    __shared__ float swsum[2];

    float myl1 = 0.f, myd = 0.f;
    if (t < NN) {
        const float a = l1_ws[b * NN + t];
        const float c = l2_ws[b * NN + t];
        myl1 = a; myd = a - c;
        sd[t] = myd; sl2[t] = c;
    }
    __syncthreads();

    if (t < NN) {
        int rank = 0;
        for (int j = 0; j < NN; ++j) {
            const float dj = sd[j];
            rank += (dj < myd) || (dj == myd && j < t);  // stable argsort
        }
        if (rank == ind_p[0]) ssel = sl2[t];
    }

    float s = myl1;
#pragma unroll
    for (int off = 32; off >= 1; off >>= 1) s += __shfl_down(s, off, 64);
    if ((t & 63) == 0) swsum[t >> 6] = s;
    __syncthreads();
    if (t == 0) {
        const float total = swsum[0] + swsum[1];
        perb[b] = total / 96.0f - ssel;
    }
}

// ---------------- Kernel 3: final mean over b ----------------
__global__ __launch_bounds__(128) void k3_final(
    const float* __restrict__ perb, float* __restrict__ out)
{
    const int t = threadIdx.x;
    float s = perb[t];
#pragma unroll
    for (int off = 32; off >= 1; off >>= 1) s += __shfl_down(s, off, 64);
    __shared__ float sw[2];
    if ((t & 63) == 0) sw[t >> 6] = s;
    __syncthreads();
    if (t == 0) out[0] = (sw[0] + sw[1]) / 128.0f;
}

extern "C" void kernel_launch(void* const* d_in, const int* in_sizes, int n_in,
                              void* d_out, int out_size, void* d_ws, size_t ws_size,
                              hipStream_t stream) {
    const float* imgs   = (const float*)d_in[0];
    const float* deltas = (const float*)d_in[1];
    const float* W      = (const float*)d_in[2];
    const float* bias   = (const float*)d_in[3];
    const int*   labels = (const int*)d_in[4];
    const int*   ind    = (const int*)d_in[5];
    float* out = (float*)d_out;

    float* l1_ws = (float*)d_ws;                   // 12288 floats
    float* l2_ws = l1_ws + NN * BB;                // 12288 floats
    float* perb  = l2_ws + NN * BB;                // 128 floats
    unsigned short* pwg = (unsigned short*)(perb + BB);  // 96 KB packed W (16B-aligned)

    k0_pack<<<dim3(24), dim3(256), 0, stream>>>(W, pwg);
    k1_mfma<<<dim3(768), dim3(512), 0, stream>>>(
        imgs, deltas, pwg, bias, labels, l1_ws, l2_ws);
    k2_select<<<dim3(BB), dim3(128), 0, stream>>>(l1_ws, l2_ws, ind, perb);
    k3_final<<<dim3(1), dim3(128), 0, stream>>>(perb, out);
}

// Round 4
// 240.849 us; speedup vs baseline: 1.0138x; 1.0037x over previous
//
#include <hip/hip_runtime.h>
#include <hip/hip_bf16.h>
#include <math.h>

#define BB 128   // batch
#define NN 96    // perturbations
#define DD 3072  // C*H*W
#define KK 10    // classes
#define SPL 8    // K-splits = waves per block in k1
#define KST 12   // MFMA K-steps per wave: 3072 / (SPL*32)

typedef short s16x8 __attribute__((ext_vector_type(8)));
typedef float f32x4 __attribute__((ext_vector_type(4)));

// ---------------- Kernel 0: pack W into B-fragment layout ----------------
// Record r (0..6143): col=r&15, quad=(r>>4)&3, kb=r>>6. 16B record holds
// bf16 W[kb*32+quad*8+j][col], j=0..7 (zero for col>=10). Lane `l` of
// K-block kb then reads record kb*64+l with ONE coalesced dwordx4.
// Also zeroes the k2/k3 completion counter (workspace is poisoned each
// iteration, so it must be re-initialized before k2 runs).
__global__ __launch_bounds__(256) void k0_pack(
    const float* __restrict__ W, unsigned short* __restrict__ pwg,
    unsigned int* __restrict__ counter)
{
    if (blockIdx.x == 0 && threadIdx.x == 0) *counter = 0u;
    const int r = blockIdx.x * 256 + threadIdx.x;   // 0..6143
    const int col  = r & 15;
    const int quad = (r >> 4) & 3;
    const int kb   = r >> 6;
    union { unsigned short us[8]; uint4 v; } rec;
#pragma unroll
    for (int j = 0; j < 8; ++j) {
        const int k = kb * 32 + quad * 8 + j;
        const float v = (col < KK) ? W[k * KK + col] : 0.0f;
        const __hip_bfloat16 h = __float2bfloat16(v);
        __builtin_memcpy(&rec.us[j], &h, 2);
    }
    ((uint4*)pwg)[r] = rec.v;
}

// ---------------- Kernel 1: MFMA logits + per-(n,b) losses ----------------
// grid = 768 blocks (one 16-row M-tile: rows r0..r0+15 = same n, b0..b0+15),
// block = 512 threads = 8 waves = 8 K-splits of 384. Each wave runs 12
// mfma_f32_16x16x32_bf16 steps; A built on the fly (clip(imgs+deltas)->bf16),
// B-frags are single coalesced 16B loads from pwg. LDS reduce + epilogue.
// (R0-exact version — best measured at 237.6 µs; R1-R3 pipeline/burst
// variants were all neutral-to-negative => k1 is at its HBM floor.)
__global__ __launch_bounds__(512) void k1_mfma(
    const float* __restrict__ imgs,    // (128, 3072)
    const float* __restrict__ deltas,  // (96, 128, 3072)
    const unsigned short* __restrict__ pwg,
    const float* __restrict__ bias,    // (10)
    const int*   __restrict__ labels,  // (128)
    float* __restrict__ l1_ws,         // (128, 96)
    float* __restrict__ l2_ws)         // (128, 96)
{
    const int lane = threadIdx.x & 63;
    const int wv   = threadIdx.x >> 6;      // 0..7 = K-split
    const int tile = blockIdx.x;            // 0..767
    const int r0   = tile * 16;
    const int n    = r0 >> 7;               // constant over tile
    const int b0   = r0 & 127;
    const int m    = lane & 15;             // A row within tile
    const int quad = lane >> 4;

    const float* ap = deltas + (size_t)(r0 + m) * DD + wv * (KST * 32) + quad * 8;
    const float* ip = imgs   + (size_t)(b0 + m) * DD + wv * (KST * 32) + quad * 8;
    const unsigned short* wp = pwg + ((size_t)(wv * KST) * 64 + lane) * 8;

    f32x4 acc = {0.f, 0.f, 0.f, 0.f};
#pragma unroll 2
    for (int s = 0; s < KST; ++s) {
        const float4 d0 = *(const float4*)(ap);
        const float4 d1 = *(const float4*)(ap + 4);
        const float4 i0 = *(const float4*)(ip);
        const float4 i1 = *(const float4*)(ip + 4);
        const s16x8 bfrag = *(const s16x8*)(wp);
        float x[8];
        x[0] = d0.x + i0.x; x[1] = d0.y + i0.y; x[2] = d0.z + i0.z; x[3] = d0.w + i0.w;
        x[4] = d1.x + i1.x; x[5] = d1.y + i1.y; x[6] = d1.z + i1.z; x[7] = d1.w + i1.w;
        s16x8 afrag;
#pragma unroll
        for (int j = 0; j < 8; ++j) {
            const float xc = fminf(fmaxf(x[j], 0.f), 1.f);
            const __hip_bfloat16 h = __float2bfloat16(xc);
            unsigned short us; __builtin_memcpy(&us, &h, 2);
            afrag[j] = (short)us;
        }
        acc = __builtin_amdgcn_mfma_f32_16x16x32_bf16(afrag, bfrag, acc, 0, 0, 0);
        ap += 32; ip += 32; wp += 512;
    }

    // C layout (m89-verified): col = lane&15, row = quad*4 + reg.
    __shared__ float sred[SPL][16][16];     // 8 KB
#pragma unroll
    for (int reg = 0; reg < 4; ++reg)
        sred[wv][quad * 4 + reg][m] = acc[reg];
    __syncthreads();

    if (wv == 0 && lane < 16) {
        const int rr = lane;                // tile row -> b = b0+rr
        float lg[KK];
#pragma unroll
        for (int k = 0; k < KK; ++k) {
            float s = 0.f;
#pragma unroll
            for (int sp = 0; sp < SPL; ++sp) s += sred[sp][rr][k];
            lg[k] = s + bias[k];
        }
        // top-1 (first max -> lower index on ties, matches lax.top_k)
        int top1 = 0; float m1 = lg[0];
#pragma unroll
        for (int k = 1; k < KK; ++k) if (lg[k] > m1) { m1 = lg[k]; top1 = k; }
        int sec = (top1 == 0) ? 1 : 0; float m2 = lg[sec];
#pragma unroll
        for (int k = 0; k < KK; ++k)
            if (k != top1 && lg[k] > m2) { m2 = lg[k]; sec = k; }
        float se = 0.f;
#pragma unroll
        for (int k = 0; k < KK; ++k) se += expf(lg[k] - m1);
        const float lse = m1 + logf(se);
        const int b = b0 + rr;
        const int lab = labels[b];
        const float loss1 = lse - lg[lab];
        const float loss2 = (top1 == lab) ? (lse - lg[sec]) : -10000.0f;
        l1_ws[b * NN + n] = loss1;
        l2_ws[b * NN + n] = loss2;
    }
}

// ---------------- Kernel 2: per-b selection + fused final mean ----------------
// 128 blocks, one per b. Each computes perb[b]; the LAST block to finish
// (device-scope atomic counter, no dispatch-order assumption) reduces
// perb[0..127] to the scalar output. Saves the separate k3 launch.
__global__ __launch_bounds__(128) void k2_select(
    const float* __restrict__ l1_ws, const float* __restrict__ l2_ws,
    const int* __restrict__ ind_p, float* __restrict__ perb,
    unsigned int* __restrict__ counter, float* __restrict__ out)
{
    const int b = blockIdx.x;
    const int t = threadIdx.x;
    __shared__ float sd[NN];
    __shared__ float sl2[NN];
    __shared__ float ssel;
    __shared__ float swsum[2];
    __shared__ unsigned int slast;

    float myl1 = 0.f, myd = 0.f;
    if (t < NN) {
        const float a = l1_ws[b * NN + t];
        const float c = l2_ws[b * NN + t];
        myl1 = a; myd = a - c;
        sd[t] = myd; sl2[t] = c;
    }
    __syncthreads();

    if (t < NN) {
        int rank = 0;
        for (int j = 0; j < NN; ++j) {
            const float dj = sd[j];
            rank += (dj < myd) || (dj == myd && j < t);  // stable argsort
        }
        if (rank == ind_p[0]) ssel = sl2[t];
    }

    float s = myl1;
#pragma unroll
    for (int off = 32; off >= 1; off >>= 1) s += __shfl_down(s, off, 64);
    if ((t & 63) == 0) swsum[t >> 6] = s;
    __syncthreads();
    if (t == 0) {
        const float total = swsum[0] + swsum[1];
        perb[b] = total / 96.0f - ssel;
        __threadfence();                       // publish perb[b] device-wide
        const unsigned int prev = atomicAdd(counter, 1u);
        slast = (prev == BB - 1) ? 1u : 0u;    // am I the last block?
    }
    __syncthreads();

    if (slast) {
        __threadfence();                       // acquire other blocks' perb
        float v = perb[t];                     // t in 0..127
#pragma unroll
        for (int off = 32; off >= 1; off >>= 1) v += __shfl_down(v, off, 64);
        if ((t & 63) == 0) swsum[t >> 6] = v;
        __syncthreads();
        if (t == 0) out[0] = (swsum[0] + swsum[1]) / 128.0f;
    }
}

extern "C" void kernel_launch(void* const* d_in, const int* in_sizes, int n_in,
                              void* d_out, int out_size, void* d_ws, size_t ws_size,
                              hipStream_t stream) {
    const float* imgs   = (const float*)d_in[0];
    const float* deltas = (const float*)d_in[1];
    const float* W      = (const float*)d_in[2];
    const float* bias   = (const float*)d_in[3];
    const int*   labels = (const int*)d_in[4];
    const int*   ind    = (const int*)d_in[5];
    float* out = (float*)d_out;

    float* l1_ws = (float*)d_ws;                   // 12288 floats
    float* l2_ws = l1_ws + NN * BB;                // 12288 floats
    float* perb  = l2_ws + NN * BB;                // 128 floats
    unsigned int* counter = (unsigned int*)(perb + BB);  // 1 uint (zeroed in k0)
    unsigned short* pwg = (unsigned short*)(counter + 4); // 96 KB packed W (16B-aligned)

    k0_pack<<<dim3(24), dim3(256), 0, stream>>>(W, pwg, counter);
    k1_mfma<<<dim3(768), dim3(512), 0, stream>>>(
        imgs, deltas, pwg, bias, labels, l1_ws, l2_ws);
    k2_select<<<dim3(BB), dim3(128), 0, stream>>>(
        l1_ws, l2_ws, ind, perb, counter, out);
}